// Round 7
// baseline (423.788 us; speedup 1.0000x reference)
//
#include <hip/hip_runtime.h>
#include <math.h>

// Problem constants: qlen=2048, bsz=2, d_model=1024, n_head=16, d_head=64,
// d_inner=4096. w_heads row (i,b): [q:1024][k:1024][v:1024], head n at n*64.

typedef __attribute__((ext_vector_type(8))) short short8;
typedef __attribute__((ext_vector_type(4))) float floatx4;

__device__ inline unsigned short f2bf(float f) {
  union { float f; unsigned u; } v; v.f = f;
  unsigned r = v.u + 0x7FFFu + ((v.u >> 16) & 1u);
  return (unsigned short)(r >> 16);
}
__device__ inline float bf2f(unsigned short u) {
  union { unsigned u; float f; } v; v.u = ((unsigned)u) << 16; return v.f;
}

#define G2L(gp, lp)                                                  \
  __builtin_amdgcn_global_load_lds(                                  \
      (const __attribute__((address_space(1))) void*)(gp),           \
      (__attribute__((address_space(3))) void*)(lp), 16, 0, 0)

// ---------------------------------------------------------------------------
// Fused prep: bf16 casts of w (blocks 0-4095) and r (4096-6143), plus five
// transpose-casts fp32 [K][N] -> bf16 [N][K] (blocks 6144-9471).
// ---------------------------------------------------------------------------
__global__ __launch_bounds__(256) void prep_kernel(
    const float* __restrict__ w, unsigned short* __restrict__ wb,
    const float* __restrict__ r, unsigned short* __restrict__ rb,
    const float* __restrict__ qkv_w, unsigned short* __restrict__ qkvT,
    const float* __restrict__ r_net_w, unsigned short* __restrict__ rnetT,
    const float* __restrict__ o_w, unsigned short* __restrict__ owT,
    const float* __restrict__ ffn_w1, unsigned short* __restrict__ w1T,
    const float* __restrict__ ffn_w2, unsigned short* __restrict__ w2T) {
  __shared__ __align__(16) unsigned short Ts[64][68];
  const int blk = blockIdx.x;
  const int t = threadIdx.x;
  if (blk < 6144) {  // elementwise casts
    const float* in = blk < 4096 ? w : r;
    unsigned short* outp = blk < 4096 ? wb : rb;
    const int i = (blk < 4096 ? blk : blk - 4096) * 256 + t;
    float4 v = ((const float4*)in)[i];
    ((ushort4*)outp)[i] =
        make_ushort4(f2bf(v.x), f2bf(v.y), f2bf(v.z), f2bf(v.w));
    return;
  }
  const float* src; unsigned short* dst; int K, N, idx;
  if (blk < 6912)      { src = qkv_w;   dst = qkvT;  K = 1024; N = 3072; idx = blk - 6144; }
  else if (blk < 7168) { src = r_net_w; dst = rnetT; K = 1024; N = 1024; idx = blk - 6912; }
  else if (blk < 7424) { src = o_w;     dst = owT;   K = 1024; N = 1024; idx = blk - 7168; }
  else if (blk < 8448) { src = ffn_w1;  dst = w1T;   K = 1024; N = 4096; idx = blk - 7424; }
  else                 { src = ffn_w2;  dst = w2T;   K = 4096; N = 1024; idx = blk - 8448; }
  const int nbx = N >> 6;
  const int k0 = (idx / nbx) * 64, n0 = (idx % nbx) * 64;
  const int rr = t >> 4, c = (t & 15) * 4;
#pragma unroll
  for (int rb2 = 0; rb2 < 64; rb2 += 16) {
    float4 v = *(const float4*)(src + (size_t)(k0 + rb2 + rr) * N + n0 + c);
    *(ushort4*)&Ts[rb2 + rr][c] =
        make_ushort4(f2bf(v.x), f2bf(v.y), f2bf(v.z), f2bf(v.w));
  }
  __syncthreads();
#pragma unroll
  for (int rb2 = 0; rb2 < 64; rb2 += 16) {
    const int nn = rb2 + rr;
    ushort4 o = make_ushort4(Ts[c + 0][nn], Ts[c + 1][nn],
                             Ts[c + 2][nn], Ts[c + 3][nn]);
    *(ushort4*)(dst + (size_t)(n0 + nn) * K + k0 + c) = o;
  }
}

// ---------------------------------------------------------------------------
// bf16 MFMA GEMM body (128x128 tile, 4 waves): kept for o_w (and ffn2
// fallback when workspace is small). C = A @ Bt^T, split-K via kz.
// Row stride 64B (== 16 mod 32 banks) -> naturally conflict-free b128 reads.
// ---------------------------------------------------------------------------
template<int BIAS, int RELU, int OUT_BF16>
__device__ __forceinline__ void bgemm_body(
    const unsigned short* __restrict__ A, const unsigned short* __restrict__ Bt,
    const float* __restrict__ bias, void* __restrict__ C,
    int M, int N, int Kstride, int Klen, size_t psize,
    int bx, int by, int kz,
    unsigned short* As, unsigned short* Bs) {
  const int t = threadIdx.x;
  const int wv = t >> 6, lane = t & 63, quad = lane >> 4, lq = lane & 15;
  const int m0 = by * 128, n0 = bx * 128;
  const int wvm = (wv >> 1) * 64, wvn = (wv & 1) * 64;

  const int srow = t >> 2;
  const int scol = (t & 3) * 8;
  const size_t koff = (size_t)kz * Klen;
  const unsigned short* Ag = A + (size_t)(m0 + srow) * Kstride + scol + koff;
  const unsigned short* Bg = Bt + (size_t)(n0 + srow) * Kstride + scol + koff;
  unsigned short* AsW0 = As + (size_t)wv * 512;           // sub-tile 0
  unsigned short* AsW1 = As + 4096 + (size_t)wv * 512;    // sub-tile 1
  unsigned short* BsW0 = Bs + (size_t)wv * 512;
  unsigned short* BsW1 = Bs + 4096 + (size_t)wv * 512;

  floatx4 acc[4][4];
#pragma unroll
  for (int am = 0; am < 4; ++am)
#pragma unroll
    for (int bn = 0; bn < 4; ++bn) acc[am][bn] = (floatx4){0.f, 0.f, 0.f, 0.f};

  for (int k0 = 0; k0 < Klen; k0 += 64) {
    __syncthreads();
    G2L(Ag + k0, AsW0);
    G2L(Ag + (size_t)64 * Kstride + k0, AsW0 + 64 * 32);
    G2L(Ag + k0 + 32, AsW1);
    G2L(Ag + (size_t)64 * Kstride + k0 + 32, AsW1 + 64 * 32);
    G2L(Bg + k0, BsW0);
    G2L(Bg + (size_t)64 * Kstride + k0, BsW0 + 64 * 32);
    G2L(Bg + k0 + 32, BsW1);
    G2L(Bg + (size_t)64 * Kstride + k0 + 32, BsW1 + 64 * 32);
    __syncthreads();

#pragma unroll
    for (int s = 0; s < 2; ++s) {
      const unsigned short* Asub = s ? As + 4096 : As;
      const unsigned short* Bsub = s ? Bs + 4096 : Bs;
      short8 af[4], bf[4];
#pragma unroll
      for (int am = 0; am < 4; ++am)
        af[am] = *(const short8*)&Asub[(wvm + am * 16 + lq) * 32 + quad * 8];
#pragma unroll
      for (int bn = 0; bn < 4; ++bn)
        bf[bn] = *(const short8*)&Bsub[(wvn + bn * 16 + lq) * 32 + quad * 8];
#pragma unroll
      for (int am = 0; am < 4; ++am)
#pragma unroll
        for (int bn = 0; bn < 4; ++bn)
          acc[am][bn] = __builtin_amdgcn_mfma_f32_16x16x32_bf16(
              af[am], bf[bn], acc[am][bn], 0, 0, 0);
    }
  }

  float bs[4] = {0.f, 0.f, 0.f, 0.f};
  if (BIAS) {
    if (kz == 0) {
#pragma unroll
      for (int bn = 0; bn < 4; ++bn) bs[bn] = bias[n0 + wvn + bn * 16 + lq];
    }
  }
  float* Cf = (float*)C + (size_t)kz * psize;
#pragma unroll
  for (int am = 0; am < 4; ++am) {
#pragma unroll
    for (int u = 0; u < 4; ++u) {
      const size_t row = m0 + wvm + am * 16 + quad * 4 + u;
#pragma unroll
      for (int bn = 0; bn < 4; ++bn) {
        const size_t col = n0 + wvn + bn * 16 + lq;
        float v = acc[am][bn][u];
        if (BIAS) v += bs[bn];
        if (RELU) v = fmaxf(v, 0.f);
        if (OUT_BF16) ((unsigned short*)C)[row * N + col] = f2bf(v);
        else          Cf[row * N + col] = v;
      }
    }
  }
}

template<int BIAS, int RELU, int OUT_BF16>
__global__ __launch_bounds__(256) void bgemm_kernel(
    const unsigned short* __restrict__ A, const unsigned short* __restrict__ Bt,
    const float* __restrict__ bias, void* __restrict__ C,
    int M, int N, int Kstride, int Klen, size_t psize) {
  __shared__ __align__(16) unsigned short As[2 * 128 * 32];
  __shared__ __align__(16) unsigned short Bs[2 * 128 * 32];
  bgemm_body<BIAS, RELU, OUT_BF16>(A, Bt, bias, C, M, N, Kstride, Klen, psize,
                                   blockIdx.x, blockIdx.y, blockIdx.z, As, Bs);
}

// ---------------------------------------------------------------------------
// 256x256 8-PHASE GEMM (T2+T3+T4+T5), round-6 verified: counted vmcnt(2) at
// phases 4/8 only; 3-bit row-key LDS swizzle (c0 = (quad^(lq&7))*8, second
// half at c0^32) with inverse-swizzled global source (rule #21). 8 lanes per
// 16B slot = wave64 b128 floor, bank-balanced.
// ---------------------------------------------------------------------------
template<int BIAS, int RELU, int OUT_BF16>
__device__ __forceinline__ void gemm256p8_body(
    const unsigned short* __restrict__ A, const unsigned short* __restrict__ Bt,
    const float* __restrict__ bias, void* __restrict__ C,
    int N, int Kstride, int Klen, int bx, int by,
    unsigned short* As0, unsigned short* Bs0,
    unsigned short* As1, unsigned short* Bs1) {
  const int t = threadIdx.x;
  const int wv = t >> 6, lane = t & 63, quad = lane >> 4, lq = lane & 15;
  const int wr = wv >> 2, wc = wv & 3;
  const int m0 = by * 256, n0 = bx * 256;

  const int srow = t >> 3;
  const int scol = (((t & 7) ^ (srow & 7)) * 8);  // inverse-swizzled source
  const unsigned short* Ag = A + (size_t)(m0 + srow) * Kstride + scol;
  const unsigned short* Bg = Bt + (size_t)(n0 + srow) * Kstride + scol;
  const int c0 = ((quad ^ (lq & 7)) * 8);         // swizzled read col (elems)

  floatx4 acc[8][4];
#pragma unroll
  for (int am = 0; am < 8; ++am)
#pragma unroll
    for (int bn = 0; bn < 4; ++bn) acc[am][bn] = (floatx4){0.f, 0.f, 0.f, 0.f};

  short8 af[8], bfA[4], bfB[4];

#define STG(dst, gp, rbase, kofs)                                            \
  do {                                                                       \
    G2L((gp) + (size_t)(rbase) * Kstride + (kofs),                           \
        (dst) + (rbase) * 64 + wv * 512);                                    \
    G2L((gp) + (size_t)((rbase) + 64) * Kstride + (kofs),                    \
        (dst) + ((rbase) + 64) * 64 + wv * 512);                             \
  } while (0)

#define LDAF(buf, ah)                                                        \
  _Pragma("unroll")                                                          \
  for (int i_ = 0; i_ < 4; ++i_) {                                           \
    const int ar_ = (wr * 128 + (ah) * 64 + i_ * 16 + lq) * 64;              \
    af[i_ * 2 + 0] = *(const short8*)&(buf)[ar_ + c0];                       \
    af[i_ * 2 + 1] = *(const short8*)&(buf)[ar_ + (c0 ^ 32)];                \
  }

#define LDBF(dst, buf, bh)                                                   \
  _Pragma("unroll")                                                          \
  for (int i_ = 0; i_ < 2; ++i_) {                                           \
    const int br_ = (wc * 64 + (bh) * 32 + i_ * 16 + lq) * 64;               \
    dst[i_ * 2 + 0] = *(const short8*)&(buf)[br_ + c0];                      \
    dst[i_ * 2 + 1] = *(const short8*)&(buf)[br_ + (c0 ^ 32)];               \
  }

#define MM(ah, bh, bfX)                                                      \
  __builtin_amdgcn_s_setprio(1);                                             \
  _Pragma("unroll")                                                          \
  for (int i_ = 0; i_ < 4; ++i_)                                             \
    _Pragma("unroll")                                                        \
    for (int j_ = 0; j_ < 2; ++j_) {                                         \
      acc[(ah) * 4 + i_][(bh) * 2 + j_] =                                    \
          __builtin_amdgcn_mfma_f32_16x16x32_bf16(                           \
              af[i_ * 2 + 0], bfX[j_ * 2 + 0],                               \
              acc[(ah) * 4 + i_][(bh) * 2 + j_], 0, 0, 0);                   \
      acc[(ah) * 4 + i_][(bh) * 2 + j_] =                                    \
          __builtin_amdgcn_mfma_f32_16x16x32_bf16(                           \
              af[i_ * 2 + 1], bfX[j_ * 2 + 1],                               \
              acc[(ah) * 4 + i_][(bh) * 2 + j_], 0, 0, 0);                   \
    }                                                                        \
  __builtin_amdgcn_s_setprio(0);

#define BAR() __builtin_amdgcn_s_barrier()
#define VM2() asm volatile("s_waitcnt vmcnt(2)" ::: "memory")
#define VM0() asm volatile("s_waitcnt vmcnt(0)" ::: "memory")

  const int NI = Klen >> 7;  // iterations of 2 K-tiles

  STG(As0, Ag, 0, 0);   STG(Bs0, Bg, 0, 0);
  STG(As0, Ag, 128, 0); STG(Bs0, Bg, 128, 0);
  STG(As1, Ag, 0, 64);
  VM2();
  BAR();

  for (int it = 0; it < NI; ++it) {
    const int ke = it * 128;
    const bool stg = (it + 1 < NI);

    // P0
    LDAF(As0, 0); LDBF(bfA, Bs0, 0);
    STG(Bs1, Bg, 0, ke + 64);
    BAR(); MM(0, 0, bfA); BAR();
    // P1
    LDBF(bfB, Bs0, 1);
    STG(As1, Ag, 128, ke + 64);
    BAR(); MM(0, 1, bfB); BAR();
    // P2
    LDAF(As0, 1);
    STG(Bs1, Bg, 128, ke + 64);
    BAR(); MM(1, 1, bfB); BAR();
    // P3 (no ds-reads: af holds a1, bfA still holds b0)
    if (stg) STG(As0, Ag, 0, ke + 128);
    BAR(); MM(1, 0, bfA);
    if (stg) VM2(); else VM0();
    BAR();
    // P4
    LDAF(As1, 0); LDBF(bfA, Bs1, 0);
    if (stg) STG(Bs0, Bg, 0, ke + 128);
    BAR(); MM(0, 0, bfA); BAR();
    // P5
    LDBF(bfB, Bs1, 1);
    if (stg) STG(As0, Ag, 128, ke + 128);
    BAR(); MM(0, 1, bfB); BAR();
    // P6
    LDAF(As1, 1);
    if (stg) STG(Bs0, Bg, 128, ke + 128);
    BAR(); MM(1, 1, bfB); BAR();
    // P7
    if (stg) STG(As1, Ag, 0, ke + 192);
    BAR(); MM(1, 0, bfA);
    if (stg) VM2(); else VM0();
    BAR();
  }

#undef STG
#undef LDAF
#undef LDBF
#undef MM
#undef BAR
#undef VM2
#undef VM0

  float bs[4] = {0.f, 0.f, 0.f, 0.f};
  if (BIAS && bias) {
#pragma unroll
    for (int bn = 0; bn < 4; ++bn) bs[bn] = bias[n0 + wc * 64 + bn * 16 + lq];
  }
#pragma unroll
  for (int am = 0; am < 8; ++am) {
#pragma unroll
    for (int u = 0; u < 4; ++u) {
      const size_t row = m0 + wr * 128 + am * 16 + quad * 4 + u;
#pragma unroll
      for (int bn = 0; bn < 4; ++bn) {
        const size_t col = n0 + wc * 64 + bn * 16 + lq;
        float v = acc[am][bn][u];
        if (BIAS) v += bs[bn];
        if (RELU) v = fmaxf(v, 0.f);
        if (OUT_BF16) ((unsigned short*)C)[row * N + col] = f2bf(v);
        else          ((float*)C)[row * N + col] = v;
      }
    }
  }
}

template<int BIAS, int RELU, int OUT_BF16>
__global__ __launch_bounds__(512, 2) void gemm256p8_kernel(
    const unsigned short* __restrict__ A, const unsigned short* __restrict__ Bt,
    const float* __restrict__ bias, void* __restrict__ C, int N, int K) {
  __shared__ __align__(16) unsigned short As[2][256 * 64];
  __shared__ __align__(16) unsigned short Bs[2][256 * 64];
  gemm256p8_body<BIAS, RELU, OUT_BF16>(A, Bt, bias, C, N, K, K,
                                       blockIdx.x, blockIdx.y,
                                       As[0], Bs[0], As[1], Bs[1]);
}

// Split-K variant: chunk kz = blockIdx.z covers K cols [kz*Klen, +Klen),
// writes fp32 partials at C + kz*psize. Bias applied only in chunk 0.
template<int BIAS, int RELU>
__global__ __launch_bounds__(512, 2) void gemm256p8_splitk_kernel(
    const unsigned short* __restrict__ A, const unsigned short* __restrict__ Bt,
    const float* __restrict__ bias, float* __restrict__ C,
    int N, int Kstride, int Klen, size_t psize) {
  __shared__ __align__(16) unsigned short As[2][256 * 64];
  __shared__ __align__(16) unsigned short Bs[2][256 * 64];
  const int kz = blockIdx.z;
  gemm256p8_body<BIAS, RELU, 0>(A + (size_t)kz * Klen, Bt + (size_t)kz * Klen,
                                kz == 0 ? bias : nullptr, C + kz * psize,
                                N, Kstride, Klen, blockIdx.x, blockIdx.y,
                                As[0], Bs[0], As[1], Bs[1]);
}

// Merged qkv (192 blocks, 16x12) + r_net (32 blocks, 8x4), 8-phase path.
__global__ __launch_bounds__(512, 2) void qkv_rk256_kernel(
    const unsigned short* __restrict__ wb, const unsigned short* __restrict__ qkvT,
    unsigned short* __restrict__ w_heads,
    const unsigned short* __restrict__ rbf, const unsigned short* __restrict__ rnetT,
    unsigned short* __restrict__ rk) {
  __shared__ __align__(16) unsigned short As[2][256 * 64];
  __shared__ __align__(16) unsigned short Bs[2][256 * 64];
  const int bid = blockIdx.x;
  if (bid < 192) {
    gemm256p8_body<0, 0, 1>(wb, qkvT, nullptr, w_heads, 3072, 1024, 1024,
                            bid % 12, bid / 12, As[0], Bs[0], As[1], Bs[1]);
  } else {
    const int b2 = bid - 192;
    gemm256p8_body<0, 0, 1>(rbf, rnetT, nullptr, rk, 1024, 1024, 1024,
                            b2 % 4, b2 / 4, As[0], Bs[0], As[1], Bs[1]);
  }
}

// ---------------------------------------------------------------------------
// MFMA bf16 flash attention, Transformer-XL relative shift (bf16 I/O).
// Round-7: SPLIT-KV LOAD BALANCE. Old grid had per-block jt counts 2..32
// (heavy it=15 = 32 jt) -> makespan set by stragglers (Occupancy 28%).
// This softmax tracks no running max, so partial (o,l) over a KV sub-range
// are ADDITIVE. New grid = 768 blocks, LPT order:
//   g <  512: heavy halves. it = 15 - (g>>6) in 15..8, h=(g>>5)&1,
//             bnb=g&31; jt in [h*(it+1), (h+1)*(it+1))  (9..16 jt each).
//             Epilogue writes fp32 partials (o rows + l) to pf[g].
//   g >= 512: light tiles. it = 7 - ((g-512)>>5) in 7..0, bnb=(g-512)&31;
//             jt in [0, 2it+2) (2..16 jt). Direct normalized avec write.
// attn_combine_kernel sums the two halves per heavy tile and normalizes.
// Max job 16 jt (was 32); 8704 total jt-units / 512 resident slots = 17.
// Inner loop is byte-identical to the verified round-6 kernel.
// ---------------------------------------------------------------------------
__global__ __launch_bounds__(512, 4) void attn_mfma_kernel(
    const unsigned short* __restrict__ w_heads,
    const unsigned short* __restrict__ r_k,
    const float* __restrict__ r_w_bias, const float* __restrict__ r_r_bias,
    unsigned short* __restrict__ attn_vec, float* __restrict__ pf) {
  __shared__ __align__(16) unsigned short Ks[64 * 72];      //  9216 B
  __shared__ __align__(16) unsigned short Vt[64 * 72];      //  9216 B [d][j]
  __shared__ __align__(16) unsigned short Rb[256 * 72];     // 36864 B circular
  __shared__ __align__(16) unsigned short Pl[8 * 16 * 72];  // 18432 B per-wave

  const int t = threadIdx.x;
  const int wv = t >> 6, lane = t & 63, quad = lane >> 4, lq = lane & 15;
  const int g = blockIdx.x;

  int it, bnb, jt0, jtE;
  bool heavy;
  if (g < 512) {
    heavy = true;
    it = 15 - (g >> 6);            // 15..8, largest first (LPT)
    const int h = (g >> 5) & 1;
    bnb = g & 31;
    jt0 = h * (it + 1);
    jtE = jt0 + (it + 1);
  } else {
    heavy = false;
    const int g2 = g - 512;
    it = 7 - (g2 >> 5);            // 7..0, largest lights backfill first
    bnb = g2 & 31;
    jt0 = 0;
    jtE = 2 * it + 2;
  }
  const int b = bnb & 1, n = bnb >> 1;
  const int i0 = it * 128, iw = i0 + wv * 16;

  // Staging coordinates (512 threads cover a 64x64 bf16 tile in one shot).
  const int kr = t >> 3, kc8 = (t & 7) * 8;   // K / r_k row + 16B chunk
  const int vj = t & 31, vc = (t >> 5) * 4;   // V row-pair + 4 d-cols

  // Persistent Q fragments (A-layout): Qw = q + r_w_bias, Qr = q + r_r_bias.
  short8 qw[2], qr[2];
  {
    const unsigned short* qrow =
        w_heads + (size_t)((iw + lq) * 2 + b) * 3072 + n * 64;
    short8 a0 = *(const short8*)(qrow + quad * 8);
    short8 a1 = *(const short8*)(qrow + 32 + quad * 8);
    const float* wbp = r_w_bias + n * 64;
    const float* rbp = r_r_bias + n * 64;
#pragma unroll
    for (int j = 0; j < 8; ++j) {
      const int k0 = quad * 8 + j, k1 = 32 + quad * 8 + j;
      const float q0 = bf2f((unsigned short)a0[j]);
      const float q1 = bf2f((unsigned short)a1[j]);
      qw[0][j] = (short)f2bf(q0 + wbp[k0]);
      qr[0][j] = (short)f2bf(q0 + rbp[k0]);
      qw[1][j] = (short)f2bf(q1 + wbp[k1]);
      qr[1][j] = (short)f2bf(q1 + rbp[k1]);
    }
  }

  floatx4 o[4];
#pragma unroll
  for (int dt = 0; dt < 4; ++dt) o[dt] = (floatx4){0.f, 0.f, 0.f, 0.f};
  float lrow[4] = {0.f, 0.f, 0.f, 0.f};

  unsigned short* Pw = Pl + wv * (16 * 72);
  const int wb2 = 112 - wv * 16;  // wave band offset (8 waves)

  // Shuffle-gather constants: row r=quad*4+u, shift s=15-r;
  // src lane = quad*16+((s+lq)&15); use next tile if (s+lq)>=16.
  int g_idx[4]; bool g_hi[4];
#pragma unroll
  for (int u = 0; u < 4; ++u) {
    const int s = 15 - (quad * 4 + u);
    g_idx[u] = quad * 16 + ((s + lq) & 15);
    g_hi[u] = (s + lq) >= 16;
  }

  const int pbase0 = 1920 - i0;   // batch-0 global row; multiple of 64, >= 0
  const int j0s = jt0 * 64;       // first KV column of this block's range

  // Prologue: stage r_k batches jt0, jt0+1 directly (rows <= 2047: max row
  // = pbase0 + 64*(jt0+1) + 127 <= 1983+64 for all (it,h) -- verified).
#pragma unroll
  for (int bq = 0; bq < 2; ++bq) {
    const int row = pbase0 + j0s + bq * 64 + kr;
    const int slot = row & 255;
    *(short8*)&Rb[slot * 72 + kc8] =
        *(const short8*)(r_k + (size_t)row * 1024 + n * 64 + kc8);
  }
  // Prefetch tile jt0's K/V and r_k batch jt0+2 into registers.
  short8 sK, sR;
  ushort4 sVl, sVh;
  {
    const unsigned short* kb =
        w_heads + (size_t)((j0s + kr) * 2 + b) * 3072 + n * 64 + 1024 + kc8;
    sK = *(const short8*)kb;
    const unsigned short* vbp =
        w_heads + (size_t)((j0s + 2 * vj) * 2 + b) * 3072 + n * 64 + 2048 + vc;
    sVl = *(const ushort4*)vbp;
    sVh = *(const ushort4*)(vbp + 2 * 3072);
    int pg = pbase0 + j0s + 128 + kr; if (pg > 2047) pg = 2047;
    sR = *(const short8*)(r_k + (size_t)pg * 1024 + n * 64 + kc8);
  }

  for (int jt = jt0; jt < jtE; ++jt) {
    const int j0 = jt * 64;
    const int pbase = pbase0 + 64 * jt;  // window base (local rows 0..191)

    // (A) prior tile's LDS consumers done. Bare s_barrier: the in-flight
    // global prefetch is NOT drained here.
    asm volatile("" ::: "memory");
    __builtin_amdgcn_s_barrier();
    asm volatile("" ::: "memory");

    // --- Write staged registers to LDS ---
    *(short8*)&Ks[kr * 72 + kc8] = sK;
#pragma unroll
    for (int i2 = 0; i2 < 4; ++i2)
      *(unsigned*)&Vt[(vc + i2) * 72 + 2 * vj] =
          (unsigned)sVl[i2] | ((unsigned)sVh[i2] << 16);
    {
      const int slot = (pbase + 128 + kr) & 255;  // batch jt+2
      *(short8*)&Rb[slot * 72 + kc8] = sR;
    }

    // --- Issue next tile's global loads (consumed next iteration) ---
    if (jt + 1 < jtE) {
      const int j0n = j0 + 64;
      const unsigned short* kb =
          w_heads + (size_t)((j0n + kr) * 2 + b) * 3072 + n * 64 + 1024 + kc8;
      sK = *(const short8*)kb;
      const unsigned short* vbp =
          w_heads + (size_t)((j0n + 2 * vj) * 2 + b) * 3072 + n * 64 + 2048 + vc;
      sVl = *(const ushort4*)vbp;
      sVh = *(const ushort4*)(vbp + 2 * 3072);
      int pg = pbase + 192 + kr; if (pg > 2047) pg = 2047;
      sR = *(const short8*)(r_k + (size_t)pg * 1024 + n * 64 + kc8);
    }

    // (B) LDS tile ready: lgkm-only drain publishes the ds_writes; the
    // just-issued global loads stay in flight across the barrier.
    asm volatile("s_waitcnt lgkmcnt(0)" ::: "memory");
    __builtin_amdgcn_s_barrier();
    asm volatile("" ::: "memory");

    // --- AC = Qw . K^T ---
    floatx4 ac[4];
#pragma unroll
    for (int ct = 0; ct < 4; ++ct) {
      short8 b0 = *(const short8*)&Ks[(ct * 16 + lq) * 72 + quad * 8];
      short8 b1 = *(const short8*)&Ks[(ct * 16 + lq) * 72 + 32 + quad * 8];
      floatx4 z = (floatx4){0.f, 0.f, 0.f, 0.f};
      z = __builtin_amdgcn_mfma_f32_16x16x32_bf16(qw[0], b0, z, 0, 0, 0);
      z = __builtin_amdgcn_mfma_f32_16x16x32_bf16(qw[1], b1, z, 0, 0, 0);
      ac[ct] = z;
    }
    // --- T = Qr . Rband^T (5 p-tiles over this wave's 80-wide band) ---
    floatx4 Tt[5];
#pragma unroll
    for (int pt = 0; pt < 5; ++pt) {
      const int slot = (pbase + wb2 + pt * 16 + lq) & 255;
      short8 b0 = *(const short8*)&Rb[slot * 72 + quad * 8];
      short8 b1 = *(const short8*)&Rb[slot * 72 + 32 + quad * 8];
      floatx4 z = (floatx4){0.f, 0.f, 0.f, 0.f};
      z = __builtin_amdgcn_mfma_f32_16x16x32_bf16(qr[0], b0, z, 0, 0, 0);
      z = __builtin_amdgcn_mfma_f32_16x16x32_bf16(qr[1], b1, z, 0, 0, 0);
      Tt[pt] = z;
    }

    // --- p = 2^((AC+BD)*0.125*log2e), store immediately. Interior tiles
    // skip the causal mask (wave-uniform branch).
    const bool interior = (j0 + 63 <= iw);
    if (interior) {
#pragma unroll
      for (int u = 0; u < 4; ++u) {
        const int r = quad * 4 + u;
        float sh[5];
#pragma unroll
        for (int pt = 0; pt < 5; ++pt) sh[pt] = __shfl(Tt[pt][u], g_idx[u]);
#pragma unroll
        for (int ct = 0; ct < 4; ++ct) {
          const float bd = g_hi[u] ? sh[ct + 1] : sh[ct];
          const float xs = (ac[ct][u] + bd) * 0.18033688011112042f;
          float pr; asm("v_exp_f32 %0, %1" : "=v"(pr) : "v"(xs));
          Pw[r * 72 + ct * 16 + lq] = f2bf(pr);
          lrow[u] += pr;
        }
      }
    } else {
#pragma unroll
      for (int u = 0; u < 4; ++u) {
        const int r = quad * 4 + u, i = iw + r;
        float sh[5];
#pragma unroll
        for (int pt = 0; pt < 5; ++pt) sh[pt] = __shfl(Tt[pt][u], g_idx[u]);
#pragma unroll
        for (int ct = 0; ct < 4; ++ct) {
          const float bd = g_hi[u] ? sh[ct + 1] : sh[ct];
          const int j = j0 + ct * 16 + lq;
          const float xs = (ac[ct][u] + bd) * 0.18033688011112042f;
          float pr; asm("v_exp_f32 %0, %1" : "=v"(pr) : "v"(xs));
          pr = (j <= i) ? pr : 0.f;
          Pw[r * 72 + ct * 16 + lq] = f2bf(pr);
          lrow[u] += pr;
        }
      }
    }

    // P strip is per-wave private: wave-local lgkm drain only (vmcnt
    // untouched so the prefetch stays in flight).
    __builtin_amdgcn_s_waitcnt(0xC07F);

    short8 pA0 = *(const short8*)&Pw[lq * 72 + quad * 8];
    short8 pA1 = *(const short8*)&Pw[lq * 72 + 32 + quad * 8];
#pragma unroll
    for (int dt = 0; dt < 4; ++dt) {
      short8 v0 = *(const short8*)&Vt[(dt * 16 + lq) * 72 + quad * 8];
      short8 v1 = *(const short8*)&Vt[(dt * 16 + lq) * 72 + 32 + quad * 8];
      o[dt] = __builtin_amdgcn_mfma_f32_16x16x32_bf16(pA0, v0, o[dt], 0, 0, 0);
      o[dt] = __builtin_amdgcn_mfma_f32_16x16x32_bf16(pA1, v1, o[dt], 0, 0, 0);
    }
  }

  // Epilogue: quad-group row-sum reduction, then either direct normalized
  // write (light) or fp32 partial (o rows + l) to pf[g] (heavy).
  if (heavy) {
    float* pfb = pf + (size_t)g * (128 * 72);
#pragma unroll
    for (int u = 0; u < 4; ++u) {
      float l = lrow[u];
      l += __shfl_xor(l, 1);
      l += __shfl_xor(l, 2);
      l += __shfl_xor(l, 4);
      l += __shfl_xor(l, 8);
      const int rl = wv * 16 + quad * 4 + u;
      float* prow = pfb + (size_t)rl * 72;
#pragma unroll
      for (int dt = 0; dt < 4; ++dt) prow[dt * 16 + lq] = o[dt][u];
      if (lq == 0) prow[64] = l;
    }
  } else {
#pragma unroll
    for (int u = 0; u < 4; ++u) {
      float l = lrow[u];
      l += __shfl_xor(l, 1);
      l += __shfl_xor(l, 2);
      l += __shfl_xor(l, 4);
      l += __shfl_xor(l, 8);
      const float linv = 1.f / l;
      const int i = iw + quad * 4 + u;
      unsigned short* op = attn_vec + (size_t)(i * 2 + b) * 1024 + n * 64 + lq;
#pragma unroll
      for (int dt = 0; dt < 4; ++dt) op[dt * 16] = f2bf(o[dt][u] * linv);
    }
  }
}

// Combine the two KV-halves of each heavy tile: avec = (oA+oB)/(lA+lB).
// 256 blocks = (8 heavy its x 32 bn); thread t: row t>>1, d-half (t&1)*32.
__global__ __launch_bounds__(256) void attn_combine_kernel(
    const float* __restrict__ pf, unsigned short* __restrict__ attn_vec) {
  const int c = blockIdx.x;
  const int t = threadIdx.x;
  const int ht = c >> 5, bnb = c & 31;
  const int it = 15 - ht;                  // matches attn heavy mapping
  const int b = bnb & 1, n = bnb >> 1;
  const int ga = ht * 64 + bnb, gb = ga + 32;
  const int r = t >> 1, dh = (t & 1) * 32;
  const float* pa = pf + ((size_t)ga * 128 + r) * 72;
  const float* pb = pf + ((size_t)gb * 128 + r) * 72;
  const float linv = 1.f / (pa[64] + pb[64]);
  const int i = it * 128 + r;
  unsigned short* op = attn_vec + (size_t)(i * 2 + b) * 1024 + n * 64 + dh;
#pragma unroll
  for (int k = 0; k < 8; ++k) {
    float4 va = *(const float4*)(pa + dh + k * 4);
    float4 vb = *(const float4*)(pb + dh + k * 4);
    *(ushort4*)(op + k * 4) = make_ushort4(
        f2bf((va.x + vb.x) * linv), f2bf((va.y + vb.y) * linv),
        f2bf((va.z + vb.z) * linv), f2bf((va.w + vb.w) * linv));
  }
}

// ---------------------------------------------------------------------------
// out = LayerNorm(X + R0 [+ R1 + R2 + R3]) * g + b, row length 1024.
// ---------------------------------------------------------------------------
__global__ __launch_bounds__(256) void ln_res_kernel(
    const float* __restrict__ X, const float* __restrict__ R0,
    const float* __restrict__ R1, const float* __restrict__ R2,
    const float* __restrict__ R3,
    const float* __restrict__ g, const float* __restrict__ bta,
    float* __restrict__ out, unsigned short* __restrict__ out_bf) {
  const int row = blockIdx.x;
  const int t = threadIdx.x;
  float4 xv = ((const float4*)(X + (size_t)row * 1024))[t];
  float4 rv = ((const float4*)(R0 + (size_t)row * 1024))[t];
  float4 v = make_float4(xv.x + rv.x, xv.y + rv.y, xv.z + rv.z, xv.w + rv.w);
  if (R1) {
    float4 r2 = ((const float4*)(R1 + (size_t)row * 1024))[t];
    v.x += r2.x; v.y += r2.y; v.z += r2.z; v.w += r2.w;
  }
  if (R2) {
    float4 r2 = ((const float4*)(R2 + (size_t)row * 1024))[t];
    v.x += r2.x; v.y += r2.y; v.z += r2.z; v.w += r2.w;
  }
  if (R3) {
    float4 r2 = ((const float4*)(R3 + (size_t)row * 1024))[t];
    v.x += r2.x; v.y += r2.y; v.z += r2.z; v.w += r2.w;
  }
  float s  = v.x + v.y + v.z + v.w;
  float sq = v.x * v.x + v.y * v.y + v.z * v.z + v.w * v.w;
#pragma unroll
  for (int off = 32; off > 0; off >>= 1) {
    s  += __shfl_xor(s, off);
    sq += __shfl_xor(sq, off);
  }
  __shared__ float ss[4], ssq[4];
  const int wid = t >> 6;
  if ((t & 63) == 0) { ss[wid] = s; ssq[wid] = sq; }
  __syncthreads();
  s  = ss[0] + ss[1] + ss[2] + ss[3];
  sq = ssq[0] + ssq[1] + ssq[2] + ssq[3];
  const float mean = s * (1.f / 1024.f);
  const float var  = sq * (1.f / 1024.f) - mean * mean;
  const float inv  = rsqrtf(var + 1e-5f);
  float4 gv = ((const float4*)g)[t];
  float4 bv = ((const float4*)bta)[t];
  float4 ov = make_float4((v.x - mean) * inv * gv.x + bv.x,
                          (v.y - mean) * inv * gv.y + bv.y,
                          (v.z - mean) * inv * gv.z + bv.z,
                          (v.w - mean) * inv * gv.w + bv.w);
  ((float4*)(out + (size_t)row * 1024))[t] = ov;
  if (out_bf)
    ((ushort4*)(out_bf + (size_t)row * 1024))[t] =
        make_ushort4(f2bf(ov.x), f2bf(ov.y), f2bf(ov.z), f2bf(ov.w));
}

// ---------------------------------------------------------------------------
extern "C" void kernel_launch(void* const* d_in, const int* in_sizes, int n_in,
                              void* d_out, int out_size, void* d_ws, size_t ws_size,
                              hipStream_t stream) {
  (void)in_sizes; (void)n_in; (void)out_size;
  const float* w        = (const float*)d_in[0];   // [2048,2,1024]
  const float* r        = (const float*)d_in[1];   // [2048,1024]
  const float* r_w_bias = (const float*)d_in[2];
  const float* r_r_bias = (const float*)d_in[3];
  // d_in[4] = attn_mask (causal; recomputed in-kernel)
  const float* qkv_w    = (const float*)d_in[5];   // [1024,3072]
  const float* r_net_w  = (const float*)d_in[6];   // [1024,1024]
  const float* o_w      = (const float*)d_in[7];   // [1024,1024]
  const float* ln1_g    = (const float*)d_in[8];
  const float* ln1_b    = (const float*)d_in[9];
  const float* ffn_w1   = (const float*)d_in[10];  // [1024,4096]
  const float* ffn_b1   = (const float*)d_in[11];
  const float* ffn_w2   = (const float*)d_in[12];  // [4096,1024]
  const float* ffn_b2   = (const float*)d_in[13];
  const float* ln2_g    = (const float*)d_in[14];
  const float* ln2_b    = (const float*)d_in[15];
  float* out = (float*)d_out;

  // Workspace overlays (MB offsets; lifetimes in comments).
  // attn phase live set: w_heads 0-24, pf 24-43, avec 64-72, rk 76-80.
  char* base = (char*)d_ws;
  const size_t MB = (size_t)1 << 20;
  unsigned short* w_heads = (unsigned short*)(base + 0);        // 0-24  [qkv..attn]
  float*          pf      = (float*)(base + 24 * MB);           // 24-43 [attn..combine]
  float*          aout0   = (float*)(base + 0);                 // 0-16  [ow..ln1]
  float*          aout1   = (float*)(base + 16 * MB);           // 16-32 [ow..ln1]
  unsigned short* h1      = (unsigned short*)(base + 0);        // 0-32  [ffn1..ffn2]
  float*          x       = (float*)(base + 32 * MB);           // 32-48 [ln1..ln2]
  unsigned short* w2T     = (unsigned short*)(base + 48 * MB);  // 48-56 [prep..ffn2]
  unsigned short* w1T     = (unsigned short*)(base + 56 * MB);  // 56-64 [prep..ffn1]
  float*          core0   = (float*)(base + 56 * MB);           // 56-72 [ffn2..ln2]
  float*          core1   = (float*)(base + 72 * MB);           // 72-88 [ffn2..ln2]
  float*          core2   = (float*)(base + 88 * MB);           // 88-104 [ffn2..ln2, big ws]
  float*          core3   = (float*)(base + 104 * MB);          // 104-120 [ffn2..ln2, big ws]
  unsigned short* wb      = (unsigned short*)(base + 64 * MB);  // 64-72 [prep..qkv]
  unsigned short* avec    = (unsigned short*)(base + 64 * MB);  // 64-72 [attn..ow]
  unsigned short* rb      = (unsigned short*)(base + 72 * MB);  // 72-76 [prep..rnet]
  unsigned short* xb      = (unsigned short*)(base + 72 * MB);  // 72-80 [ln1..ffn1]
  unsigned short* rk      = (unsigned short*)(base + 76 * MB);  // 76-80 [rnet..attn]
  unsigned short* qkvT    = (unsigned short*)(base + 80 * MB);  // 80-86 [prep..qkv]
  unsigned short* owT     = (unsigned short*)(base + 86 * MB);  // 86-88 [prep..ow]
  unsigned short* rnetT   = (unsigned short*)(base + 88 * MB);  // 88-90 [prep..rnet]

  const bool big_ws = ws_size >= (size_t)120 * MB;

  dim3 blk(256);
  prep_kernel<<<9472, blk, 0, stream>>>(w, wb, r, rb, qkv_w, qkvT,
                                        r_net_w, rnetT, o_w, owT,
                                        ffn_w1, w1T, ffn_w2, w2T);

  qkv_rk256_kernel<<<224, 512, 0, stream>>>(wb, qkvT, w_heads, rb, rnetT, rk);
  attn_mfma_kernel<<<768, 512, 0, stream>>>(
      w_heads, rk, r_w_bias, r_r_bias, avec, pf);
  attn_combine_kernel<<<256, blk, 0, stream>>>(pf, avec);
  bgemm_kernel<0, 0, 0><<<dim3(8, 32, 2), blk, 0, stream>>>(
      avec, owT, nullptr, aout0, 4096, 1024, 1024, 512, (size_t)4096 * 1024);
  ln_res_kernel<<<4096, blk, 0, stream>>>(w, aout0, aout1, nullptr, nullptr,
                                          ln1_g, ln1_b, x, xb);
  gemm256p8_kernel<1, 1, 1><<<dim3(16, 16), 512, 0, stream>>>(
      xb, w1T, ffn_b1, h1, 4096, 1024);
  if (big_ws) {
    gemm256p8_splitk_kernel<1, 0><<<dim3(4, 16, 4), 512, 0, stream>>>(
        h1, w2T, ffn_b2, core0, 1024, 4096, 1024, (size_t)4096 * 1024);
    ln_res_kernel<<<4096, blk, 0, stream>>>(x, core0, core1, core2, core3,
                                            ln2_g, ln2_b, out, nullptr);
  } else {
    bgemm_kernel<1, 0, 0><<<dim3(8, 32, 2), blk, 0, stream>>>(
        h1, w2T, ffn_b2, core0, 4096, 1024, 4096, 2048, (size_t)4096 * 1024);
    ln_res_kernel<<<4096, blk, 0, stream>>>(x, core0, core1, nullptr, nullptr,
                                            ln2_g, ln2_b, out, nullptr);
  }
}

// Round 8
// 401.976 us; speedup vs baseline: 1.0543x; 1.0543x over previous
//
#include <hip/hip_runtime.h>
#include <math.h>

// Problem constants: qlen=2048, bsz=2, d_model=1024, n_head=16, d_head=64,
// d_inner=4096. w_heads row (i,b): [q:1024][k:1024][v:1024], head n at n*64.

typedef __attribute__((ext_vector_type(8))) short short8;
typedef __attribute__((ext_vector_type(4))) float floatx4;

__device__ inline unsigned short f2bf(float f) {
  union { float f; unsigned u; } v; v.f = f;
  unsigned r = v.u + 0x7FFFu + ((v.u >> 16) & 1u);
  return (unsigned short)(r >> 16);
}
__device__ inline float bf2f(unsigned short u) {
  union { unsigned u; float f; } v; v.u = ((unsigned)u) << 16; return v.f;
}

#define G2L(gp, lp)                                                  \
  __builtin_amdgcn_global_load_lds(                                  \
      (const __attribute__((address_space(1))) void*)(gp),           \
      (__attribute__((address_space(3))) void*)(lp), 16, 0, 0)

// ---------------------------------------------------------------------------
// Fused prep (round-8: ffn_w1/ffn_w2 transposes MOVED into the attn launch
// as backfill — grid is now 7424): bf16 casts of w (blocks 0-4095) and r
// (4096-6143), plus qkv/rnet/ow transpose-casts (6144-7423).
// ---------------------------------------------------------------------------
__global__ __launch_bounds__(256) void prep_kernel(
    const float* __restrict__ w, unsigned short* __restrict__ wb,
    const float* __restrict__ r, unsigned short* __restrict__ rb,
    const float* __restrict__ qkv_w, unsigned short* __restrict__ qkvT,
    const float* __restrict__ r_net_w, unsigned short* __restrict__ rnetT,
    const float* __restrict__ o_w, unsigned short* __restrict__ owT) {
  __shared__ __align__(16) unsigned short Ts[64][68];
  const int blk = blockIdx.x;
  const int t = threadIdx.x;
  if (blk < 6144) {  // elementwise casts
    const float* in = blk < 4096 ? w : r;
    unsigned short* outp = blk < 4096 ? wb : rb;
    const int i = (blk < 4096 ? blk : blk - 4096) * 256 + t;
    float4 v = ((const float4*)in)[i];
    ((ushort4*)outp)[i] =
        make_ushort4(f2bf(v.x), f2bf(v.y), f2bf(v.z), f2bf(v.w));
    return;
  }
  const float* src; unsigned short* dst; int K, N, idx;
  if (blk < 6912)      { src = qkv_w;   dst = qkvT;  K = 1024; N = 3072; idx = blk - 6144; }
  else if (blk < 7168) { src = r_net_w; dst = rnetT; K = 1024; N = 1024; idx = blk - 6912; }
  else                 { src = o_w;     dst = owT;   K = 1024; N = 1024; idx = blk - 7168; }
  const int nbx = N >> 6;
  const int k0 = (idx / nbx) * 64, n0 = (idx % nbx) * 64;
  const int rr = t >> 4, c = (t & 15) * 4;
#pragma unroll
  for (int rb2 = 0; rb2 < 64; rb2 += 16) {
    float4 v = *(const float4*)(src + (size_t)(k0 + rb2 + rr) * N + n0 + c);
    *(ushort4*)&Ts[rb2 + rr][c] =
        make_ushort4(f2bf(v.x), f2bf(v.y), f2bf(v.z), f2bf(v.w));
  }
  __syncthreads();
#pragma unroll
  for (int rb2 = 0; rb2 < 64; rb2 += 16) {
    const int nn = rb2 + rr;
    ushort4 o = make_ushort4(Ts[c + 0][nn], Ts[c + 1][nn],
                             Ts[c + 2][nn], Ts[c + 3][nn]);
    *(ushort4*)(dst + (size_t)(n0 + nn) * K + k0 + c) = o;
  }
}

// ---------------------------------------------------------------------------
// bf16 MFMA GEMM body (128x128 tile, 4 waves): kept for o_w (and ffn2
// fallback when workspace is small). C = A @ Bt^T, split-K via kz.
// Row stride 64B (== 16 mod 32 banks) -> naturally conflict-free b128 reads.
// ---------------------------------------------------------------------------
template<int BIAS, int RELU, int OUT_BF16>
__device__ __forceinline__ void bgemm_body(
    const unsigned short* __restrict__ A, const unsigned short* __restrict__ Bt,
    const float* __restrict__ bias, void* __restrict__ C,
    int M, int N, int Kstride, int Klen, size_t psize,
    int bx, int by, int kz,
    unsigned short* As, unsigned short* Bs) {
  const int t = threadIdx.x;
  const int wv = t >> 6, lane = t & 63, quad = lane >> 4, lq = lane & 15;
  const int m0 = by * 128, n0 = bx * 128;
  const int wvm = (wv >> 1) * 64, wvn = (wv & 1) * 64;

  const int srow = t >> 2;
  const int scol = (t & 3) * 8;
  const size_t koff = (size_t)kz * Klen;
  const unsigned short* Ag = A + (size_t)(m0 + srow) * Kstride + scol + koff;
  const unsigned short* Bg = Bt + (size_t)(n0 + srow) * Kstride + scol + koff;
  unsigned short* AsW0 = As + (size_t)wv * 512;           // sub-tile 0
  unsigned short* AsW1 = As + 4096 + (size_t)wv * 512;    // sub-tile 1
  unsigned short* BsW0 = Bs + (size_t)wv * 512;
  unsigned short* BsW1 = Bs + 4096 + (size_t)wv * 512;

  floatx4 acc[4][4];
#pragma unroll
  for (int am = 0; am < 4; ++am)
#pragma unroll
    for (int bn = 0; bn < 4; ++bn) acc[am][bn] = (floatx4){0.f, 0.f, 0.f, 0.f};

  for (int k0 = 0; k0 < Klen; k0 += 64) {
    __syncthreads();
    G2L(Ag + k0, AsW0);
    G2L(Ag + (size_t)64 * Kstride + k0, AsW0 + 64 * 32);
    G2L(Ag + k0 + 32, AsW1);
    G2L(Ag + (size_t)64 * Kstride + k0 + 32, AsW1 + 64 * 32);
    G2L(Bg + k0, BsW0);
    G2L(Bg + (size_t)64 * Kstride + k0, BsW0 + 64 * 32);
    G2L(Bg + k0 + 32, BsW1);
    G2L(Bg + (size_t)64 * Kstride + k0 + 32, BsW1 + 64 * 32);
    __syncthreads();

#pragma unroll
    for (int s = 0; s < 2; ++s) {
      const unsigned short* Asub = s ? As + 4096 : As;
      const unsigned short* Bsub = s ? Bs + 4096 : Bs;
      short8 af[4], bf[4];
#pragma unroll
      for (int am = 0; am < 4; ++am)
        af[am] = *(const short8*)&Asub[(wvm + am * 16 + lq) * 32 + quad * 8];
#pragma unroll
      for (int bn = 0; bn < 4; ++bn)
        bf[bn] = *(const short8*)&Bsub[(wvn + bn * 16 + lq) * 32 + quad * 8];
#pragma unroll
      for (int am = 0; am < 4; ++am)
#pragma unroll
        for (int bn = 0; bn < 4; ++bn)
          acc[am][bn] = __builtin_amdgcn_mfma_f32_16x16x32_bf16(
              af[am], bf[bn], acc[am][bn], 0, 0, 0);
    }
  }

  float bs[4] = {0.f, 0.f, 0.f, 0.f};
  if (BIAS) {
    if (kz == 0) {
#pragma unroll
      for (int bn = 0; bn < 4; ++bn) bs[bn] = bias[n0 + wvn + bn * 16 + lq];
    }
  }
  float* Cf = (float*)C + (size_t)kz * psize;
#pragma unroll
  for (int am = 0; am < 4; ++am) {
#pragma unroll
    for (int u = 0; u < 4; ++u) {
      const size_t row = m0 + wvm + am * 16 + quad * 4 + u;
#pragma unroll
      for (int bn = 0; bn < 4; ++bn) {
        const size_t col = n0 + wvn + bn * 16 + lq;
        float v = acc[am][bn][u];
        if (BIAS) v += bs[bn];
        if (RELU) v = fmaxf(v, 0.f);
        if (OUT_BF16) ((unsigned short*)C)[row * N + col] = f2bf(v);
        else          Cf[row * N + col] = v;
      }
    }
  }
}

template<int BIAS, int RELU, int OUT_BF16>
__global__ __launch_bounds__(256) void bgemm_kernel(
    const unsigned short* __restrict__ A, const unsigned short* __restrict__ Bt,
    const float* __restrict__ bias, void* __restrict__ C,
    int M, int N, int Kstride, int Klen, size_t psize) {
  __shared__ __align__(16) unsigned short As[2 * 128 * 32];
  __shared__ __align__(16) unsigned short Bs[2 * 128 * 32];
  bgemm_body<BIAS, RELU, OUT_BF16>(A, Bt, bias, C, M, N, Kstride, Klen, psize,
                                   blockIdx.x, blockIdx.y, blockIdx.z, As, Bs);
}

// ---------------------------------------------------------------------------
// 256x256 8-PHASE GEMM (T2+T3+T4+T5), round-6 verified: counted vmcnt(2) at
// phases 4/8 only; 3-bit row-key LDS swizzle (c0 = (quad^(lq&7))*8, second
// half at c0^32) with inverse-swizzled global source (rule #21). 8 lanes per
// 16B slot = wave64 b128 floor, bank-balanced.
// ---------------------------------------------------------------------------
template<int BIAS, int RELU, int OUT_BF16>
__device__ __forceinline__ void gemm256p8_body(
    const unsigned short* __restrict__ A, const unsigned short* __restrict__ Bt,
    const float* __restrict__ bias, void* __restrict__ C,
    int N, int Kstride, int Klen, int bx, int by,
    unsigned short* As0, unsigned short* Bs0,
    unsigned short* As1, unsigned short* Bs1) {
  const int t = threadIdx.x;
  const int wv = t >> 6, lane = t & 63, quad = lane >> 4, lq = lane & 15;
  const int wr = wv >> 2, wc = wv & 3;
  const int m0 = by * 256, n0 = bx * 256;

  const int srow = t >> 3;
  const int scol = (((t & 7) ^ (srow & 7)) * 8);  // inverse-swizzled source
  const unsigned short* Ag = A + (size_t)(m0 + srow) * Kstride + scol;
  const unsigned short* Bg = Bt + (size_t)(n0 + srow) * Kstride + scol;
  const int c0 = ((quad ^ (lq & 7)) * 8);         // swizzled read col (elems)

  floatx4 acc[8][4];
#pragma unroll
  for (int am = 0; am < 8; ++am)
#pragma unroll
    for (int bn = 0; bn < 4; ++bn) acc[am][bn] = (floatx4){0.f, 0.f, 0.f, 0.f};

  short8 af[8], bfA[4], bfB[4];

#define STG(dst, gp, rbase, kofs)                                            \
  do {                                                                       \
    G2L((gp) + (size_t)(rbase) * Kstride + (kofs),                           \
        (dst) + (rbase) * 64 + wv * 512);                                    \
    G2L((gp) + (size_t)((rbase) + 64) * Kstride + (kofs),                    \
        (dst) + ((rbase) + 64) * 64 + wv * 512);                             \
  } while (0)

#define LDAF(buf, ah)                                                        \
  _Pragma("unroll")                                                          \
  for (int i_ = 0; i_ < 4; ++i_) {                                           \
    const int ar_ = (wr * 128 + (ah) * 64 + i_ * 16 + lq) * 64;              \
    af[i_ * 2 + 0] = *(const short8*)&(buf)[ar_ + c0];                       \
    af[i_ * 2 + 1] = *(const short8*)&(buf)[ar_ + (c0 ^ 32)];                \
  }

#define LDBF(dst, buf, bh)                                                   \
  _Pragma("unroll")                                                          \
  for (int i_ = 0; i_ < 2; ++i_) {                                           \
    const int br_ = (wc * 64 + (bh) * 32 + i_ * 16 + lq) * 64;               \
    dst[i_ * 2 + 0] = *(const short8*)&(buf)[br_ + c0];                      \
    dst[i_ * 2 + 1] = *(const short8*)&(buf)[br_ + (c0 ^ 32)];               \
  }

#define MM(ah, bh, bfX)                                                      \
  __builtin_amdgcn_s_setprio(1);                                             \
  _Pragma("unroll")                                                          \
  for (int i_ = 0; i_ < 4; ++i_)                                             \
    _Pragma("unroll")                                                        \
    for (int j_ = 0; j_ < 2; ++j_) {                                         \
      acc[(ah) * 4 + i_][(bh) * 2 + j_] =                                    \
          __builtin_amdgcn_mfma_f32_16x16x32_bf16(                           \
              af[i_ * 2 + 0], bfX[j_ * 2 + 0],                               \
              acc[(ah) * 4 + i_][(bh) * 2 + j_], 0, 0, 0);                   \
      acc[(ah) * 4 + i_][(bh) * 2 + j_] =                                    \
          __builtin_amdgcn_mfma_f32_16x16x32_bf16(                           \
              af[i_ * 2 + 1], bfX[j_ * 2 + 1],                               \
              acc[(ah) * 4 + i_][(bh) * 2 + j_], 0, 0, 0);                   \
    }                                                                        \
  __builtin_amdgcn_s_setprio(0);

#define BAR() __builtin_amdgcn_s_barrier()
#define VM2() asm volatile("s_waitcnt vmcnt(2)" ::: "memory")
#define VM0() asm volatile("s_waitcnt vmcnt(0)" ::: "memory")

  const int NI = Klen >> 7;  // iterations of 2 K-tiles

  STG(As0, Ag, 0, 0);   STG(Bs0, Bg, 0, 0);
  STG(As0, Ag, 128, 0); STG(Bs0, Bg, 128, 0);
  STG(As1, Ag, 0, 64);
  VM2();
  BAR();

  for (int it = 0; it < NI; ++it) {
    const int ke = it * 128;
    const bool stg = (it + 1 < NI);

    // P0
    LDAF(As0, 0); LDBF(bfA, Bs0, 0);
    STG(Bs1, Bg, 0, ke + 64);
    BAR(); MM(0, 0, bfA); BAR();
    // P1
    LDBF(bfB, Bs0, 1);
    STG(As1, Ag, 128, ke + 64);
    BAR(); MM(0, 1, bfB); BAR();
    // P2
    LDAF(As0, 1);
    STG(Bs1, Bg, 128, ke + 64);
    BAR(); MM(1, 1, bfB); BAR();
    // P3 (no ds-reads: af holds a1, bfA still holds b0)
    if (stg) STG(As0, Ag, 0, ke + 128);
    BAR(); MM(1, 0, bfA);
    if (stg) VM2(); else VM0();
    BAR();
    // P4
    LDAF(As1, 0); LDBF(bfA, Bs1, 0);
    if (stg) STG(Bs0, Bg, 0, ke + 128);
    BAR(); MM(0, 0, bfA); BAR();
    // P5
    LDBF(bfB, Bs1, 1);
    if (stg) STG(As0, Ag, 128, ke + 128);
    BAR(); MM(0, 1, bfB); BAR();
    // P6
    LDAF(As1, 1);
    if (stg) STG(Bs0, Bg, 128, ke + 128);
    BAR(); MM(1, 1, bfB); BAR();
    // P7
    if (stg) STG(As1, Ag, 0, ke + 192);
    BAR(); MM(1, 0, bfA);
    if (stg) VM2(); else VM0();
    BAR();
  }

#undef STG
#undef LDAF
#undef LDBF
#undef MM
#undef BAR
#undef VM2
#undef VM0

  float bs[4] = {0.f, 0.f, 0.f, 0.f};
  if (BIAS && bias) {
#pragma unroll
    for (int bn = 0; bn < 4; ++bn) bs[bn] = bias[n0 + wc * 64 + bn * 16 + lq];
  }
#pragma unroll
  for (int am = 0; am < 8; ++am) {
#pragma unroll
    for (int u = 0; u < 4; ++u) {
      const size_t row = m0 + wr * 128 + am * 16 + quad * 4 + u;
#pragma unroll
      for (int bn = 0; bn < 4; ++bn) {
        const size_t col = n0 + wc * 64 + bn * 16 + lq;
        float v = acc[am][bn][u];
        if (BIAS) v += bs[bn];
        if (RELU) v = fmaxf(v, 0.f);
        if (OUT_BF16) ((unsigned short*)C)[row * N + col] = f2bf(v);
        else          ((float*)C)[row * N + col] = v;
      }
    }
  }
}

template<int BIAS, int RELU, int OUT_BF16>
__global__ __launch_bounds__(512, 2) void gemm256p8_kernel(
    const unsigned short* __restrict__ A, const unsigned short* __restrict__ Bt,
    const float* __restrict__ bias, void* __restrict__ C, int N, int K) {
  __shared__ __align__(16) unsigned short As[2][256 * 64];
  __shared__ __align__(16) unsigned short Bs[2][256 * 64];
  gemm256p8_body<BIAS, RELU, OUT_BF16>(A, Bt, bias, C, N, K, K,
                                       blockIdx.x, blockIdx.y,
                                       As[0], Bs[0], As[1], Bs[1]);
}

// Split-K variant: chunk kz = blockIdx.z covers K cols [kz*Klen, +Klen),
// writes fp32 partials at C + kz*psize. Bias applied only in chunk 0.
template<int BIAS, int RELU>
__global__ __launch_bounds__(512, 2) void gemm256p8_splitk_kernel(
    const unsigned short* __restrict__ A, const unsigned short* __restrict__ Bt,
    const float* __restrict__ bias, float* __restrict__ C,
    int N, int Kstride, int Klen, size_t psize) {
  __shared__ __align__(16) unsigned short As[2][256 * 64];
  __shared__ __align__(16) unsigned short Bs[2][256 * 64];
  const int kz = blockIdx.z;
  gemm256p8_body<BIAS, RELU, 0>(A + (size_t)kz * Klen, Bt + (size_t)kz * Klen,
                                kz == 0 ? bias : nullptr, C + kz * psize,
                                N, Kstride, Klen, blockIdx.x, blockIdx.y,
                                As[0], Bs[0], As[1], Bs[1]);
}

// Merged qkv (192 blocks, 16x12) + r_net (32 blocks, 8x4), 8-phase path.
__global__ __launch_bounds__(512, 2) void qkv_rk256_kernel(
    const unsigned short* __restrict__ wb, const unsigned short* __restrict__ qkvT,
    unsigned short* __restrict__ w_heads,
    const unsigned short* __restrict__ rbf, const unsigned short* __restrict__ rnetT,
    unsigned short* __restrict__ rk) {
  __shared__ __align__(16) unsigned short As[2][256 * 64];
  __shared__ __align__(16) unsigned short Bs[2][256 * 64];
  const int bid = blockIdx.x;
  if (bid < 192) {
    gemm256p8_body<0, 0, 1>(wb, qkvT, nullptr, w_heads, 3072, 1024, 1024,
                            bid % 12, bid / 12, As[0], Bs[0], As[1], Bs[1]);
  } else {
    const int b2 = bid - 192;
    gemm256p8_body<0, 0, 1>(rbf, rnetT, nullptr, rk, 1024, 1024, 1024,
                            b2 % 4, b2 / 4, As[0], Bs[0], As[1], Bs[1]);
  }
}

// ---------------------------------------------------------------------------
// MFMA bf16 flash attention, Transformer-XL relative shift (bf16 I/O).
// Round-8: attn body REVERTED to round-6 exactly (split-KV removed: round-7
// proved occupancy is capped by the per-jt serial chain at 2 blocks/CU, not
// tail imbalance — balancing bought nothing and the partials cost 11us).
// NEW: blocks 512..2559 are the ffn_w1/ffn_w2 transpose-casts, moved out of
// prep. attn blocks dispatch first (g<512); transposes BACKFILL freed CUs
// while heavy attn blocks run — attn leaves HBM at 3.5%, so the pure-BW
// transpose work hides under it instead of serializing in prep.
// ---------------------------------------------------------------------------
__global__ __launch_bounds__(512, 4) void attn_mfma_kernel(
    const unsigned short* __restrict__ w_heads,
    const unsigned short* __restrict__ r_k,
    const float* __restrict__ r_w_bias, const float* __restrict__ r_r_bias,
    unsigned short* __restrict__ attn_vec,
    const float* __restrict__ ffn_w1, unsigned short* __restrict__ w1T,
    const float* __restrict__ ffn_w2, unsigned short* __restrict__ w2T) {
  __shared__ __align__(16) unsigned short Ks[64 * 72];      //  9216 B
  __shared__ __align__(16) unsigned short Vt[64 * 72];      //  9216 B [d][j]
  __shared__ __align__(16) unsigned short Rb[256 * 72];     // 36864 B circular
  __shared__ __align__(16) unsigned short Pl[8 * 16 * 72];  // 18432 B per-wave

  const int t = threadIdx.x;
  const int g = blockIdx.x;

  if (g >= 512) {
    // ---- Backfill: 64x64 transpose-cast fp32 [K][N] -> bf16 [N][K] ----
    // 512 threads: rr = t>>4 in 0..31 covers 32 rows/iter, 2 iters.
    unsigned short (*Ts)[68] = reinterpret_cast<unsigned short(*)[68]>(Ks);
    const int g2 = g - 512;
    const float* src; unsigned short* dst; int K, N, idx;
    if (g2 < 1024) { src = ffn_w1; dst = w1T; K = 1024; N = 4096; idx = g2; }
    else           { src = ffn_w2; dst = w2T; K = 4096; N = 1024; idx = g2 - 1024; }
    const int nbx = N >> 6;
    const int k0 = (idx / nbx) * 64, n0 = (idx % nbx) * 64;
    const int rr = t >> 4, c = (t & 15) * 4;
#pragma unroll
    for (int rb2 = 0; rb2 < 64; rb2 += 32) {
      float4 v = *(const float4*)(src + (size_t)(k0 + rb2 + rr) * N + n0 + c);
      *(ushort4*)&Ts[rb2 + rr][c] =
          make_ushort4(f2bf(v.x), f2bf(v.y), f2bf(v.z), f2bf(v.w));
    }
    __syncthreads();
#pragma unroll
    for (int rb2 = 0; rb2 < 64; rb2 += 32) {
      const int nn = rb2 + rr;
      ushort4 o = make_ushort4(Ts[c + 0][nn], Ts[c + 1][nn],
                               Ts[c + 2][nn], Ts[c + 3][nn]);
      *(ushort4*)(dst + (size_t)(n0 + nn) * K + k0 + c) = o;
    }
    return;
  }

  // ---- attn proper (round-6 body) ----
  const int wv = t >> 6, lane = t & 63, quad = lane >> 4, lq = lane & 15;
  const int qq = g >> 5, bnb = g & 31;
  const int it = (qq < 8) ? (15 - qq) : (qq - 8);  // pair (g,g+256) sums to 15
  const int b = bnb & 1, n = bnb >> 1;
  const int i0 = it * 128, iw = i0 + wv * 16;

  // Staging coordinates (512 threads cover a 64x64 bf16 tile in one shot).
  const int kr = t >> 3, kc8 = (t & 7) * 8;   // K / r_k row + 16B chunk
  const int vj = t & 31, vc = (t >> 5) * 4;   // V row-pair + 4 d-cols

  // Persistent Q fragments (A-layout): Qw = q + r_w_bias, Qr = q + r_r_bias.
  short8 qw[2], qr[2];
  {
    const unsigned short* qrow =
        w_heads + (size_t)((iw + lq) * 2 + b) * 3072 + n * 64;
    short8 a0 = *(const short8*)(qrow + quad * 8);
    short8 a1 = *(const short8*)(qrow + 32 + quad * 8);
    const float* wbp = r_w_bias + n * 64;
    const float* rbp = r_r_bias + n * 64;
#pragma unroll
    for (int j = 0; j < 8; ++j) {
      const int k0 = quad * 8 + j, k1 = 32 + quad * 8 + j;
      const float q0 = bf2f((unsigned short)a0[j]);
      const float q1 = bf2f((unsigned short)a1[j]);
      qw[0][j] = (short)f2bf(q0 + wbp[k0]);
      qr[0][j] = (short)f2bf(q0 + rbp[k0]);
      qw[1][j] = (short)f2bf(q1 + wbp[k1]);
      qr[1][j] = (short)f2bf(q1 + rbp[k1]);
    }
  }

  floatx4 o[4];
#pragma unroll
  for (int dt = 0; dt < 4; ++dt) o[dt] = (floatx4){0.f, 0.f, 0.f, 0.f};
  float lrow[4] = {0.f, 0.f, 0.f, 0.f};

  unsigned short* Pw = Pl + wv * (16 * 72);
  const int wb2 = 112 - wv * 16;  // wave band offset (8 waves)

  // Shuffle-gather constants: row r=quad*4+u, shift s=15-r;
  // src lane = quad*16+((s+lq)&15); use next tile if (s+lq)>=16.
  int g_idx[4]; bool g_hi[4];
#pragma unroll
  for (int u = 0; u < 4; ++u) {
    const int s = 15 - (quad * 4 + u);
    g_idx[u] = quad * 16 + ((s + lq) & 15);
    g_hi[u] = (s + lq) >= 16;
  }

  const int pbase0 = 1920 - i0;   // batch-0 global row; multiple of 64, >= 0
  const int jt_end = 2 * it + 2;

  // Prologue: stage r_k batches 0,1 directly (rows <= 2047 guaranteed).
#pragma unroll
  for (int bq = 0; bq < 2; ++bq) {
    const int row = pbase0 + bq * 64 + kr;
    const int slot = row & 255;
    *(short8*)&Rb[slot * 72 + kc8] =
        *(const short8*)(r_k + (size_t)row * 1024 + n * 64 + kc8);
  }
  // Prefetch tile 0 K/V and r_k batch 2 into registers.
  short8 sK, sR;
  ushort4 sVl, sVh;
  {
    const unsigned short* kb =
        w_heads + (size_t)(kr * 2 + b) * 3072 + n * 64 + 1024 + kc8;
    sK = *(const short8*)kb;
    const unsigned short* vbp =
        w_heads + (size_t)((2 * vj) * 2 + b) * 3072 + n * 64 + 2048 + vc;
    sVl = *(const ushort4*)vbp;
    sVh = *(const ushort4*)(vbp + 2 * 3072);
    int pg = pbase0 + 128 + kr; if (pg > 2047) pg = 2047;
    sR = *(const short8*)(r_k + (size_t)pg * 1024 + n * 64 + kc8);
  }

  for (int jt = 0; jt < jt_end; ++jt) {
    const int j0 = jt * 64;
    const int pbase = pbase0 + 64 * jt;  // window base (local rows 0..191)

    // (A) prior tile's LDS consumers done. Bare s_barrier: the in-flight
    // global prefetch is NOT drained here.
    asm volatile("" ::: "memory");
    __builtin_amdgcn_s_barrier();
    asm volatile("" ::: "memory");

    // --- Write staged registers to LDS ---
    *(short8*)&Ks[kr * 72 + kc8] = sK;
#pragma unroll
    for (int i2 = 0; i2 < 4; ++i2)
      *(unsigned*)&Vt[(vc + i2) * 72 + 2 * vj] =
          (unsigned)sVl[i2] | ((unsigned)sVh[i2] << 16);
    {
      const int slot = (pbase + 128 + kr) & 255;  // batch jt+2
      *(short8*)&Rb[slot * 72 + kc8] = sR;
    }

    // --- Issue next tile's global loads (consumed next iteration) ---
    if (jt + 1 < jt_end) {
      const int j0n = j0 + 64;
      const unsigned short* kb =
          w_heads + (size_t)((j0n + kr) * 2 + b) * 3072 + n * 64 + 1024 + kc8;
      sK = *(const short8*)kb;
      const unsigned short* vbp =
          w_heads + (size_t)((j0n + 2 * vj) * 2 + b) * 3072 + n * 64 + 2048 + vc;
      sVl = *(const ushort4*)vbp;
      sVh = *(const ushort4*)(vbp + 2 * 3072);
      int pg = pbase + 192 + kr; if (pg > 2047) pg = 2047;
      sR = *(const short8*)(r_k + (size_t)pg * 1024 + n * 64 + kc8);
    }

    // (B) LDS tile ready: lgkm-only drain publishes the ds_writes; the
    // just-issued global loads stay in flight across the barrier.
    asm volatile("s_waitcnt lgkmcnt(0)" ::: "memory");
    __builtin_amdgcn_s_barrier();
    asm volatile("" ::: "memory");

    // --- AC = Qw . K^T ---
    floatx4 ac[4];
#pragma unroll
    for (int ct = 0; ct < 4; ++ct) {
      short8 b0 = *(const short8*)&Ks[(ct * 16 + lq) * 72 + quad * 8];
      short8 b1 = *(const short8*)&Ks[(ct * 16 + lq) * 72 + 32 + quad * 8];
      floatx4 z = (floatx4){0.f, 0.f, 0.f, 0.f};
      z = __builtin_amdgcn_mfma_f32_16x16x32_bf16(qw[0], b0, z, 0, 0, 0);
      z = __builtin_amdgcn_mfma_f32_16x16x32_bf16(qw[1], b1, z, 0, 0, 0);
      ac[ct] = z;
    }
    // --- T = Qr . Rband^T (5 p-tiles over this wave's 80-wide band) ---
    floatx4 Tt[5];
#pragma unroll
    for (int pt = 0; pt < 5; ++pt) {
      const int slot = (pbase + wb2 + pt * 16 + lq) & 255;
      short8 b0 = *(const short8*)&Rb[slot * 72 + quad * 8];
      short8 b1 = *(const short8*)&Rb[slot * 72 + 32 + quad * 8];
      floatx4 z = (floatx4){0.f, 0.f, 0.f, 0.f};
      z = __builtin_amdgcn_mfma_f32_16x16x32_bf16(qr[0], b0, z, 0, 0, 0);
      z = __builtin_amdgcn_mfma_f32_16x16x32_bf16(qr[1], b1, z, 0, 0, 0);
      Tt[pt] = z;
    }

    // --- p = 2^((AC+BD)*0.125*log2e), store immediately. Interior tiles
    // skip the causal mask (wave-uniform branch).
    const bool interior = (j0 + 63 <= iw);
    if (interior) {
#pragma unroll
      for (int u = 0; u < 4; ++u) {
        const int r = quad * 4 + u;
        float sh[5];
#pragma unroll
        for (int pt = 0; pt < 5; ++pt) sh[pt] = __shfl(Tt[pt][u], g_idx[u]);
#pragma unroll
        for (int ct = 0; ct < 4; ++ct) {
          const float bd = g_hi[u] ? sh[ct + 1] : sh[ct];
          const float xs = (ac[ct][u] + bd) * 0.18033688011112042f;
          float pr; asm("v_exp_f32 %0, %1" : "=v"(pr) : "v"(xs));
          Pw[r * 72 + ct * 16 + lq] = f2bf(pr);
          lrow[u] += pr;
        }
      }
    } else {
#pragma unroll
      for (int u = 0; u < 4; ++u) {
        const int r = quad * 4 + u, i = iw + r;
        float sh[5];
#pragma unroll
        for (int pt = 0; pt < 5; ++pt) sh[pt] = __shfl(Tt[pt][u], g_idx[u]);
#pragma unroll
        for (int ct = 0; ct < 4; ++ct) {
          const float bd = g_hi[u] ? sh[ct + 1] : sh[ct];
          const int j = j0 + ct * 16 + lq;
          const float xs = (ac[ct][u] + bd) * 0.18033688011112042f;
          float pr; asm("v_exp_f32 %0, %1" : "=v"(pr) : "v"(xs));
          pr = (j <= i) ? pr : 0.f;
          Pw[r * 72 + ct * 16 + lq] = f2bf(pr);
          lrow[u] += pr;
        }
      }
    }

    // P strip is per-wave private: wave-local lgkm drain only (vmcnt
    // untouched so the prefetch stays in flight).
    __builtin_amdgcn_s_waitcnt(0xC07F);

    short8 pA0 = *(const short8*)&Pw[lq * 72 + quad * 8];
    short8 pA1 = *(const short8*)&Pw[lq * 72 + 32 + quad * 8];
#pragma unroll
    for (int dt = 0; dt < 4; ++dt) {
      short8 v0 = *(const short8*)&Vt[(dt * 16 + lq) * 72 + quad * 8];
      short8 v1 = *(const short8*)&Vt[(dt * 16 + lq) * 72 + 32 + quad * 8];
      o[dt] = __builtin_amdgcn_mfma_f32_16x16x32_bf16(pA0, v0, o[dt], 0, 0, 0);
      o[dt] = __builtin_amdgcn_mfma_f32_16x16x32_bf16(pA1, v1, o[dt], 0, 0, 0);
    }
  }

  // Final row-sum reduction (within 16-lane quad groups) and store.
#pragma unroll
  for (int u = 0; u < 4; ++u) {
    float l = lrow[u];
    l += __shfl_xor(l, 1);
    l += __shfl_xor(l, 2);
    l += __shfl_xor(l, 4);
    l += __shfl_xor(l, 8);
    const float linv = 1.f / l;
    const int i = iw + quad * 4 + u;
    unsigned short* op = attn_vec + (size_t)(i * 2 + b) * 1024 + n * 64 + lq;
#pragma unroll
    for (int dt = 0; dt < 4; ++dt) op[dt * 16] = f2bf(o[dt][u] * linv);
  }
}

// ---------------------------------------------------------------------------
// out = LayerNorm(X + R0 [+ R1 + R2 + R3]) * g + b, row length 1024.
// ---------------------------------------------------------------------------
__global__ __launch_bounds__(256) void ln_res_kernel(
    const float* __restrict__ X, const float* __restrict__ R0,
    const float* __restrict__ R1, const float* __restrict__ R2,
    const float* __restrict__ R3,
    const float* __restrict__ g, const float* __restrict__ bta,
    float* __restrict__ out, unsigned short* __restrict__ out_bf) {
  const int row = blockIdx.x;
  const int t = threadIdx.x;
  float4 xv = ((const float4*)(X + (size_t)row * 1024))[t];
  float4 rv = ((const float4*)(R0 + (size_t)row * 1024))[t];
  float4 v = make_float4(xv.x + rv.x, xv.y + rv.y, xv.z + rv.z, xv.w + rv.w);
  if (R1) {
    float4 r2 = ((const float4*)(R1 + (size_t)row * 1024))[t];
    v.x += r2.x; v.y += r2.y; v.z += r2.z; v.w += r2.w;
  }
  if (R2) {
    float4 r2 = ((const float4*)(R2 + (size_t)row * 1024))[t];
    v.x += r2.x; v.y += r2.y; v.z += r2.z; v.w += r2.w;
  }
  if (R3) {
    float4 r2 = ((const float4*)(R3 + (size_t)row * 1024))[t];
    v.x += r2.x; v.y += r2.y; v.z += r2.z; v.w += r2.w;
  }
  float s  = v.x + v.y + v.z + v.w;
  float sq = v.x * v.x + v.y * v.y + v.z * v.z + v.w * v.w;
#pragma unroll
  for (int off = 32; off > 0; off >>= 1) {
    s  += __shfl_xor(s, off);
    sq += __shfl_xor(sq, off);
  }
  __shared__ float ss[4], ssq[4];
  const int wid = t >> 6;
  if ((t & 63) == 0) { ss[wid] = s; ssq[wid] = sq; }
  __syncthreads();
  s  = ss[0] + ss[1] + ss[2] + ss[3];
  sq = ssq[0] + ssq[1] + ssq[2] + ssq[3];
  const float mean = s * (1.f / 1024.f);
  const float var  = sq * (1.f / 1024.f) - mean * mean;
  const float inv  = rsqrtf(var + 1e-5f);
  float4 gv = ((const float4*)g)[t];
  float4 bv = ((const float4*)bta)[t];
  float4 ov = make_float4((v.x - mean) * inv * gv.x + bv.x,
                          (v.y - mean) * inv * gv.y + bv.y,
                          (v.z - mean) * inv * gv.z + bv.z,
                          (v.w - mean) * inv * gv.w + bv.w);
  ((float4*)(out + (size_t)row * 1024))[t] = ov;
  if (out_bf)
    ((ushort4*)(out_bf + (size_t)row * 1024))[t] =
        make_ushort4(f2bf(ov.x), f2bf(ov.y), f2bf(ov.z), f2bf(ov.w));
}

// ---------------------------------------------------------------------------
extern "C" void kernel_launch(void* const* d_in, const int* in_sizes, int n_in,
                              void* d_out, int out_size, void* d_ws, size_t ws_size,
                              hipStream_t stream) {
  (void)in_sizes; (void)n_in; (void)out_size;
  const float* w        = (const float*)d_in[0];   // [2048,2,1024]
  const float* r        = (const float*)d_in[1];   // [2048,1024]
  const float* r_w_bias = (const float*)d_in[2];
  const float* r_r_bias = (const float*)d_in[3];
  // d_in[4] = attn_mask (causal; recomputed in-kernel)
  const float* qkv_w    = (const float*)d_in[5];   // [1024,3072]
  const float* r_net_w  = (const float*)d_in[6];   // [1024,1024]
  const float* o_w      = (const float*)d_in[7];   // [1024,1024]
  const float* ln1_g    = (const float*)d_in[8];
  const float* ln1_b    = (const float*)d_in[9];
  const float* ffn_w1   = (const float*)d_in[10];  // [1024,4096]
  const float* ffn_b1   = (const float*)d_in[11];
  const float* ffn_w2   = (const float*)d_in[12];  // [4096,1024]
  const float* ffn_b2   = (const float*)d_in[13];
  const float* ln2_g    = (const float*)d_in[14];
  const float* ln2_b    = (const float*)d_in[15];
  float* out = (float*)d_out;

  // Workspace overlays (MB offsets; lifetimes in comments).
  // attn phase live set: w_heads 0-24, w1T/w2T 48-64 (written by backfill),
  // avec 64-72, rk 76-80. Base plan peaks at 90 MiB; ffn2 split-4 path
  // additionally uses 88-120 (guarded by big_ws).
  char* base = (char*)d_ws;
  const size_t MB = (size_t)1 << 20;
  unsigned short* w_heads = (unsigned short*)(base + 0);        // 0-24  [qkv..attn]
  float*          aout0   = (float*)(base + 0);                 // 0-16  [ow..ln1]
  float*          aout1   = (float*)(base + 16 * MB);           // 16-32 [ow..ln1]
  unsigned short* h1      = (unsigned short*)(base + 0);        // 0-32  [ffn1..ffn2]
  float*          x       = (float*)(base + 32 * MB);           // 32-48 [ln1..ln2]
  unsigned short* w2T     = (unsigned short*)(base + 48 * MB);  // 48-56 [attn..ffn2]
  unsigned short* w1T     = (unsigned short*)(base + 56 * MB);  // 56-64 [attn..ffn1]
  float*          core0   = (float*)(base + 56 * MB);           // 56-72 [ffn2..ln2]
  float*          core1   = (float*)(base + 72 * MB);           // 72-88 [ffn2..ln2]
  float*          core2   = (float*)(base + 88 * MB);           // 88-104 [ffn2..ln2, big ws]
  float*          core3   = (float*)(base + 104 * MB);          // 104-120 [ffn2..ln2, big ws]
  unsigned short* wb      = (unsigned short*)(base + 64 * MB);  // 64-72 [prep..qkv]
  unsigned short* avec    = (unsigned short*)(base + 64 * MB);  // 64-72 [attn..ow]
  unsigned short* rb      = (unsigned short*)(base + 72 * MB);  // 72-76 [prep..rnet]
  unsigned short* xb      = (unsigned short*)(base + 72 * MB);  // 72-80 [ln1..ffn1]
  unsigned short* rk      = (unsigned short*)(base + 76 * MB);  // 76-80 [rnet..attn]
  unsigned short* qkvT    = (unsigned short*)(base + 80 * MB);  // 80-86 [prep..qkv]
  unsigned short* owT     = (unsigned short*)(base + 86 * MB);  // 86-88 [prep..ow]
  unsigned short* rnetT   = (unsigned short*)(base + 88 * MB);  // 88-90 [prep..rnet]

  const bool big_ws = ws_size >= (size_t)120 * MB;

  dim3 blk(256);
  prep_kernel<<<7424, blk, 0, stream>>>(w, wb, r, rb, qkv_w, qkvT,
                                        r_net_w, rnetT, o_w, owT);

  qkv_rk256_kernel<<<224, 512, 0, stream>>>(wb, qkvT, w_heads, rb, rnetT, rk);
  // attn (blocks 0-511) + ffn weight transposes backfill (512-2559).
  attn_mfma_kernel<<<2560, 512, 0, stream>>>(
      w_heads, rk, r_w_bias, r_r_bias, avec, ffn_w1, w1T, ffn_w2, w2T);
  bgemm_kernel<0, 0, 0><<<dim3(8, 32, 2), blk, 0, stream>>>(
      avec, owT, nullptr, aout0, 4096, 1024, 1024, 512, (size_t)4096 * 1024);
  ln_res_kernel<<<4096, blk, 0, stream>>>(w, aout0, aout1, nullptr, nullptr,
                                          ln1_g, ln1_b, x, xb);
  gemm256p8_kernel<1, 1, 1><<<dim3(16, 16), 512, 0, stream>>>(
      xb, w1T, ffn_b1, h1, 4096, 1024);
  if (big_ws) {
    gemm256p8_splitk_kernel<1, 0><<<dim3(4, 16, 4), 512, 0, stream>>>(
        h1, w2T, ffn_b2, core0, 1024, 4096, 1024, (size_t)4096 * 1024);
    ln_res_kernel<<<4096, blk, 0, stream>>>(x, core0, core1, core2, core3,
                                            ln2_g, ln2_b, out, nullptr);
  } else {
    bgemm_kernel<1, 0, 0><<<dim3(8, 32, 2), blk, 0, stream>>>(
        h1, w2T, ffn_b2, core0, 4096, 1024, 4096, 2048, (size_t)4096 * 1024);
    ln_res_kernel<<<4096, blk, 0, stream>>>(x, core0, core1, nullptr, nullptr,
                                            ln2_g, ln2_b, out, nullptr);
  }
}